// Round 1
// baseline (291.185 us; speedup 1.0000x reference)
//
#include <hip/hip_runtime.h>
#include <hip/hip_bf16.h>
#include <cstdint>

// GQA prefill: b=2, t=1024, E=2048, NQ=32, NKV=8, HD=64. fp32 in/out, bf16 MFMA inside.

typedef __attribute__((ext_vector_type(8))) short short8;   // 8 bf16 in 4 VGPRs (MFMA A/B frag)
typedef __attribute__((ext_vector_type(4))) short short4v;
typedef __attribute__((ext_vector_type(4))) float f32x4;    // MFMA C/D frag

__device__ inline short f2b(float f) {  // fp32 -> bf16 (RNE)
  union { float f; unsigned u; } v; v.f = f;
  unsigned r = v.u + 0x7fffu + ((v.u >> 16) & 1u);
  return (short)(r >> 16);
}

__device__ inline void gl_lds16(const void* g, void* l) {
  // async global->LDS, 16B/lane; LDS dest = wave-uniform base + lane*16
  __builtin_amdgcn_global_load_lds((const __attribute__((address_space(1))) void*)g,
                                   (__attribute__((address_space(3))) void*)l,
                                   16, 0, 0);
}

// ---------------- elementwise cast x -> bf16 ----------------
__global__ void cast_x_kernel(const float* __restrict__ x, short* __restrict__ xb, int n4) {
  int i = blockIdx.x * 256 + threadIdx.x;
  if (i >= n4) return;
  float4 v = ((const float4*)x)[i];
  short4v o; o.x = f2b(v.x); o.y = f2b(v.y); o.z = f2b(v.z); o.w = f2b(v.w);
  ((short4v*)xb)[i] = o;
}

// ---------------- LDS-tiled transpose+cast: W (KxN) -> WT rows n: WT[(off+n)*stride + k] ----------------
__global__ void wtrans_kernel(const float* __restrict__ W, short* __restrict__ WT,
                              int N, int outRowOff, int outStride) {
  __shared__ float tile[64][65];
  const int nb = blockIdx.x * 64, kb = blockIdx.y * 64;
  const int tid = threadIdx.x;
  const int c = tid & 63, r0 = tid >> 6;
#pragma unroll
  for (int s = 0; s < 16; ++s) {
    int k = r0 + s * 4;
    tile[c][k] = W[(size_t)(kb + k) * N + nb + c];   // coalesced read, stride-65 LDS write
  }
  __syncthreads();
#pragma unroll
  for (int s = 0; s < 16; ++s) {
    int n = r0 + s * 4;
    WT[(size_t)(outRowOff + nb + n) * outStride + kb + c] = f2b(tile[n][c]); // coalesced write
  }
}

// ---------------- bf16 MFMA GEMM, C = A(MxK) * BT(NxK)^T + bias ----------------
// 128x128 tile / block, 4 waves (2x2), each wave 4x4 subtiles of 16x16x32.
__launch_bounds__(256, 2)
__global__ void gemm_bt(const short* __restrict__ A, const short* __restrict__ BT,
                        float* __restrict__ C, const float* __restrict__ bias,
                        int M, int N, int K) {
  __shared__ __align__(16) short lA[128 * 32];
  __shared__ __align__(16) short lB[128 * 32];
  const int tid = threadIdx.x;
  const int lane = tid & 63;
  const int wv = tid >> 6;
  const int wr = wv >> 1, wc = wv & 1;
  const int q4 = lane >> 4, l15 = lane & 15;
  const int bm = blockIdx.y * 128, bn = blockIdx.x * 128;

  const short* Ag = A + (size_t)(bm + (tid >> 2)) * K + ((tid & 3) << 3);
  const short* Bg = BT + (size_t)(bn + (tid >> 2)) * K + ((tid & 3) << 3);
  short* lA0 = lA + wv * 512;  // wave-uniform staging base
  short* lB0 = lB + wv * 512;

  f32x4 acc[4][4];
  const f32x4 fz = {0.f, 0.f, 0.f, 0.f};
#pragma unroll
  for (int i = 0; i < 4; ++i)
#pragma unroll
    for (int j = 0; j < 4; ++j) acc[i][j] = fz;

  for (int k0 = 0; k0 < K; k0 += 32) {
    gl_lds16(Ag + k0, lA0);
    gl_lds16(Ag + (size_t)64 * K + k0, lA0 + 2048);
    gl_lds16(Bg + k0, lB0);
    gl_lds16(Bg + (size_t)64 * K + k0, lB0 + 2048);
    __syncthreads();
    short8 af[4], bf[4];
#pragma unroll
    for (int i = 0; i < 4; ++i) af[i] = *(const short8*)(lA + (wr * 64 + i * 16 + l15) * 32 + q4 * 8);
#pragma unroll
    for (int i = 0; i < 4; ++i) bf[i] = *(const short8*)(lB + (wc * 64 + i * 16 + l15) * 32 + q4 * 8);
#pragma unroll
    for (int mi = 0; mi < 4; ++mi)
#pragma unroll
      for (int ni = 0; ni < 4; ++ni)
        acc[mi][ni] = __builtin_amdgcn_mfma_f32_16x16x32_bf16(af[mi], bf[ni], acc[mi][ni], 0, 0, 0);
    __syncthreads();
  }

#pragma unroll
  for (int mi = 0; mi < 4; ++mi) {
    int row = bm + wr * 64 + mi * 16 + q4 * 4;
#pragma unroll
    for (int ni = 0; ni < 4; ++ni) {
      int col = bn + wc * 64 + ni * 16 + l15;
      float bb = bias ? bias[col] : 0.f;
#pragma unroll
      for (int r = 0; r < 4; ++r)
        C[(size_t)(row + r) * N + col] = acc[mi][ni][r] + bb;
    }
  }
}

// ---------------- RoPE (+bias, + 1/8 scale folded into Q), scatter to per-head layouts ----------------
// thread -> (b, t, slot<40, d2<32); slot<32: q head; else k head.
__global__ void rope_qk(const float* __restrict__ Cqkv,
                        const float* __restrict__ bq, const float* __restrict__ bk,
                        short* __restrict__ Qb, short* __restrict__ Kb) {
  int idx = blockIdx.x * 256 + threadIdx.x;
  int d2 = idx & 31;
  int rem = idx >> 5;
  int slot = rem % 40;
  int rem2 = rem / 40;
  int t = rem2 & 1023;
  int b = rem2 >> 10;
  size_t rowbase = (size_t)(b * 1024 + t) * 3072;
  // theta = 10000^(-d2/32)
  float theta = expf(-(float)d2 * (9.210340371976184f / 32.0f));
  float ang = (float)(t + 1) * theta;
  float sn = sinf(ang), cs = cosf(ang);
  if (slot < 32) {
    int h = slot;
    int cb = h * 64 + d2;
    float x0 = Cqkv[rowbase + cb] + bq[cb];
    float x1 = Cqkv[rowbase + cb + 32] + bq[cb + 32];
    float y0 = (x0 * cs - x1 * sn) * 0.125f;  // fold 1/sqrt(HD)
    float y1 = (x1 * cs + x0 * sn) * 0.125f;
    size_t ob = ((size_t)(b * 32 + h) * 1024 + t) * 64 + d2;
    Qb[ob] = f2b(y0);
    Qb[ob + 32] = f2b(y1);
  } else {
    int h = slot - 32;
    int cb = h * 64 + d2;
    float x0 = Cqkv[rowbase + 2048 + cb] + bk[cb];
    float x1 = Cqkv[rowbase + 2048 + cb + 32] + bk[cb + 32];
    float y0 = x0 * cs - x1 * sn;
    float y1 = x1 * cs + x0 * sn;
    size_t ob = ((size_t)(b * 8 + h) * 1024 + t) * 64 + d2;
    Kb[ob] = f2b(y0);
    Kb[ob + 32] = f2b(y1);
  }
}

// ---------------- V: (b,t,hkv,d) slice of Cqkv -> VT (b,hkv,d,t) bf16 ----------------
__global__ void vtrans_kernel(const float* __restrict__ Cqkv, const float* __restrict__ bv,
                              short* __restrict__ VTb) {
  __shared__ float tile[64][65];
  const int tt = blockIdx.x, h = blockIdx.y, b = blockIdx.z;
  const int tid = threadIdx.x;
  const int d = tid & 63, r0 = tid >> 6;
#pragma unroll
  for (int s = 0; s < 16; ++s) {
    int tl = r0 + s * 4;
    tile[d][tl] = Cqkv[(size_t)(b * 1024 + tt * 64 + tl) * 3072 + 2560 + h * 64 + d] + bv[h * 64 + d];
  }
  __syncthreads();
  const int tl = tid & 63, d0 = tid >> 6;
#pragma unroll
  for (int s = 0; s < 16; ++s) {
    int dd = d0 + s * 4;
    VTb[((size_t)((b * 8 + h) * 64 + dd)) * 1024 + tt * 64 + tl] = f2b(tile[dd][tl]);
  }
}

// ---------------- flash attention, MFMA, online softmax ----------------
// block = (qt, h, b); 4 waves, wave w owns q rows [qt*64+w*16, +16).
__launch_bounds__(256, 2)
__global__ void attn_kernel(const short* __restrict__ Qb, const short* __restrict__ Kb,
                            const short* __restrict__ VTb, short* __restrict__ AO) {
  __shared__ __align__(16) short lK[64 * 64];   // [krow][d]
  __shared__ __align__(16) short lVT[64 * 64];  // [d][krow]
  __shared__ __align__(16) short lP[4][16 * 64];
  const int qt = blockIdx.x, h = blockIdx.y, b = blockIdx.z;
  const int hkv = h >> 2;
  const int tid = threadIdx.x;
  const int lane = tid & 63, w = tid >> 6;
  const int q4 = lane >> 4, l15 = lane & 15;
  const size_t qbase = (size_t)(b * 32 + h) * (1024 * 64);
  const size_t kbase = (size_t)(b * 8 + hkv) * (1024 * 64);
  const size_t vbase = (size_t)(b * 8 + hkv) * (64 * 1024);

  // Q fragments (A-operand): m=l15 (q row), k(d) = c*32 + q4*8 + j
  short8 qf0 = *(const short8*)(Qb + qbase + (size_t)(qt * 64 + w * 16 + l15) * 64 + q4 * 8);
  short8 qf1 = *(const short8*)(Qb + qbase + (size_t)(qt * 64 + w * 16 + l15) * 64 + 32 + q4 * 8);

  f32x4 o[4];
  float m_i[4], l_i[4];
  const f32x4 fz = {0.f, 0.f, 0.f, 0.f};
#pragma unroll
  for (int i = 0; i < 4; ++i) { o[i] = fz; m_i[i] = -1e30f; l_i[i] = 0.f; }

  const int vd = tid >> 3;          // VT staging row (d)
  const int vc = (tid & 7) << 3;    // VT staging col (k)

  for (int kt = 0; kt <= qt; ++kt) {
    gl_lds16(Kb + kbase + (size_t)kt * 4096 + tid * 8, lK + w * 512);
    gl_lds16(Kb + kbase + (size_t)kt * 4096 + 2048 + tid * 8, lK + 2048 + w * 512);
    gl_lds16(VTb + vbase + (size_t)vd * 1024 + kt * 64 + vc, lVT + w * 512);
    gl_lds16(VTb + vbase + (size_t)(vd + 32) * 1024 + kt * 64 + vc, lVT + 2048 + w * 512);
    __syncthreads();

    // S = Q K^T  (scale pre-folded into Q)
    f32x4 s[4];
#pragma unroll
    for (int nt = 0; nt < 4; ++nt) {
      short8 kf0 = *(const short8*)(lK + (nt * 16 + l15) * 64 + q4 * 8);
      short8 kf1 = *(const short8*)(lK + (nt * 16 + l15) * 64 + 32 + q4 * 8);
      f32x4 z = fz;
      z = __builtin_amdgcn_mfma_f32_16x16x32_bf16(qf0, kf0, z, 0, 0, 0);
      z = __builtin_amdgcn_mfma_f32_16x16x32_bf16(qf1, kf1, z, 0, 0, 0);
      s[nt] = z;
    }

    const int qrow0 = qt * 64 + w * 16 + q4 * 4;  // + r
    const int kcol0 = kt * 64 + l15;              // + nt*16
    const bool last = (kt == qt);
#pragma unroll
    for (int r = 0; r < 4; ++r) {
      float mx = -1e30f;
#pragma unroll
      for (int nt = 0; nt < 4; ++nt) {
        float v = s[nt][r];
        if (last && (kcol0 + nt * 16 > qrow0 + r)) v = -1e30f;  // causal mask
        s[nt][r] = v;
        mx = fmaxf(mx, v);
      }
      mx = fmaxf(mx, __shfl_xor(mx, 1));
      mx = fmaxf(mx, __shfl_xor(mx, 2));
      mx = fmaxf(mx, __shfl_xor(mx, 4));
      mx = fmaxf(mx, __shfl_xor(mx, 8));
      float mnew = fmaxf(m_i[r], mx);
      float alpha = __expf(m_i[r] - mnew);
      m_i[r] = mnew;
      float sum = 0.f;
#pragma unroll
      for (int nt = 0; nt < 4; ++nt) {
        float p = __expf(s[nt][r] - mnew);
        s[nt][r] = p;
        sum += p;
      }
      sum += __shfl_xor(sum, 1);
      sum += __shfl_xor(sum, 2);
      sum += __shfl_xor(sum, 4);
      sum += __shfl_xor(sum, 8);
      l_i[r] = l_i[r] * alpha + sum;
#pragma unroll
      for (int dt = 0; dt < 4; ++dt) o[dt][r] *= alpha;
    }

    // P: C-layout -> A-layout via per-wave LDS round trip (DS in-order within wave)
#pragma unroll
    for (int nt = 0; nt < 4; ++nt)
#pragma unroll
      for (int r = 0; r < 4; ++r)
        lP[w][(q4 * 4 + r) * 64 + nt * 16 + l15] = f2b(s[nt][r]);
    short8 pf0 = *(const short8*)(&lP[w][l15 * 64 + q4 * 8]);
    short8 pf1 = *(const short8*)(&lP[w][l15 * 64 + 32 + q4 * 8]);

#pragma unroll
    for (int dt = 0; dt < 4; ++dt) {
      short8 vf0 = *(const short8*)(lVT + (dt * 16 + l15) * 64 + q4 * 8);
      short8 vf1 = *(const short8*)(lVT + (dt * 16 + l15) * 64 + 32 + q4 * 8);
      o[dt] = __builtin_amdgcn_mfma_f32_16x16x32_bf16(pf0, vf0, o[dt], 0, 0, 0);
      o[dt] = __builtin_amdgcn_mfma_f32_16x16x32_bf16(pf1, vf1, o[dt], 0, 0, 0);
    }
    __syncthreads();
  }

#pragma unroll
  for (int dt = 0; dt < 4; ++dt)
#pragma unroll
    for (int r = 0; r < 4; ++r) {
      int row = qt * 64 + w * 16 + q4 * 4 + r;
      AO[(size_t)(b * 1024 + row) * 2048 + h * 64 + dt * 16 + l15] = f2b(o[dt][r] / l_i[r]);
    }
}

extern "C" void kernel_launch(void* const* d_in, const int* in_sizes, int n_in,
                              void* d_out, int out_size, void* d_ws, size_t ws_size,
                              hipStream_t stream) {
  const float* x  = (const float*)d_in[0];
  const float* wq = (const float*)d_in[1];
  const float* bq = (const float*)d_in[2];
  const float* wk = (const float*)d_in[3];
  const float* bk = (const float*)d_in[4];
  const float* wv = (const float*)d_in[5];
  const float* bv = (const float*)d_in[6];
  const float* wo = (const float*)d_in[7];
  const float* bo = (const float*)d_in[8];
  float* out = (float*)d_out;
  const int B = in_sizes[0] / (1024 * 2048);
  const int M = B * 1024;

  char* ws = (char*)d_ws;
  size_t off = 0;
  auto alloc = [&](size_t bytes) -> char* {
    char* p = ws + off;
    off += (bytes + 255) & ~(size_t)255;
    return p;
  };
  short* xb    = (short*)alloc((size_t)M * 2048 * 2);
  short* WqkvT = (short*)alloc((size_t)3072 * 2048 * 2);  // rows: 0..2048 wq^T, ..2560 wk^T, ..3072 wv^T
  short* woT   = (short*)alloc((size_t)2048 * 2048 * 2);
  float* Cqkv  = (float*)alloc((size_t)M * 3072 * 4);
  short* Qb    = (short*)alloc((size_t)B * 32 * 1024 * 64 * 2);  // (b,h,t,d)
  short* Kb    = (short*)alloc((size_t)B * 8 * 1024 * 64 * 2);   // (b,hkv,t,d)
  short* VTb   = (short*)alloc((size_t)B * 8 * 64 * 1024 * 2);   // (b,hkv,d,t)
  short* AO    = (short*)alloc((size_t)M * 2048 * 2);            // (b,t,E) bf16

  cast_x_kernel<<<(M * 2048 / 4 + 255) / 256, 256, 0, stream>>>(x, xb, M * 2048 / 4);
  wtrans_kernel<<<dim3(2048 / 64, 2048 / 64), 256, 0, stream>>>(wq, WqkvT, 2048, 0, 2048);
  wtrans_kernel<<<dim3(512 / 64, 2048 / 64), 256, 0, stream>>>(wk, WqkvT, 512, 2048, 2048);
  wtrans_kernel<<<dim3(512 / 64, 2048 / 64), 256, 0, stream>>>(wv, WqkvT, 512, 2560, 2048);
  wtrans_kernel<<<dim3(2048 / 64, 2048 / 64), 256, 0, stream>>>(wo, woT, 2048, 0, 2048);
  gemm_bt<<<dim3(3072 / 128, M / 128), 256, 0, stream>>>(xb, WqkvT, Cqkv, nullptr, M, 3072, 2048);
  rope_qk<<<(B * 1024 * 40 * 32) / 256, 256, 0, stream>>>(Cqkv, bq, bk, Qb, Kb);
  vtrans_kernel<<<dim3(16, 8, B), 256, 0, stream>>>(Cqkv, bv, VTb);
  attn_kernel<<<dim3(16, 32, B), 256, 0, stream>>>(Qb, Kb, VTb, AO);
  gemm_bt<<<dim3(2048 / 128, M / 128), 256, 0, stream>>>(AO, woT, out, bo, M, 2048, 2048);
}

// Round 2
// 280.331 us; speedup vs baseline: 1.0387x; 1.0387x over previous
//
#include <hip/hip_runtime.h>
#include <hip/hip_bf16.h>
#include <cstdint>

// GQA prefill: b=2, t=1024, E=2048, NQ=32, NKV=8, HD=64. fp32 in/out, bf16 MFMA inside.

typedef __attribute__((ext_vector_type(8))) short short8;   // 8 bf16 in 4 VGPRs (MFMA A/B frag)
typedef __attribute__((ext_vector_type(4))) short short4v;
typedef __attribute__((ext_vector_type(4))) float f32x4;    // MFMA C/D frag

__device__ inline short f2b(float f) {  // fp32 -> bf16 (RNE)
  union { float f; unsigned u; } v; v.f = f;
  unsigned r = v.u + 0x7fffu + ((v.u >> 16) & 1u);
  return (short)(r >> 16);
}

__device__ inline float exp2_fast(float x) {  // raw v_exp_f32 (2^x)
  float r;
  asm("v_exp_f32 %0, %1" : "=v"(r) : "v"(x));
  return r;
}

template <int CTRL>
__device__ inline float dpp_max_step(float x) {  // x = max(x, row_ror<CTRL>(x))
  int i = __builtin_bit_cast(int, x);
  int o = __builtin_amdgcn_update_dpp(i, i, CTRL, 0xF, 0xF, false);
  return fmaxf(x, __builtin_bit_cast(float, o));
}

__device__ inline void gl_lds16(const void* g, void* l) {
  __builtin_amdgcn_global_load_lds((const __attribute__((address_space(1))) void*)g,
                                   (__attribute__((address_space(3))) void*)l,
                                   16, 0, 0);
}

// ---------------- elementwise cast x -> bf16 ----------------
__global__ void cast_x_kernel(const float* __restrict__ x, short* __restrict__ xb, int n4) {
  int i = blockIdx.x * 256 + threadIdx.x;
  if (i >= n4) return;
  float4 v = ((const float4*)x)[i];
  short4v o; o.x = f2b(v.x); o.y = f2b(v.y); o.z = f2b(v.z); o.w = f2b(v.w);
  ((short4v*)xb)[i] = o;
}

// ---------------- LDS-tiled transpose+cast: W (KxN) -> WT rows n: WT[(off+n)*stride + k] ----------------
__global__ void wtrans_kernel(const float* __restrict__ W, short* __restrict__ WT,
                              int N, int outRowOff, int outStride) {
  __shared__ float tile[64][65];
  const int nb = blockIdx.x * 64, kb = blockIdx.y * 64;
  const int tid = threadIdx.x;
  const int c = tid & 63, r0 = tid >> 6;
#pragma unroll
  for (int s = 0; s < 16; ++s) {
    int k = r0 + s * 4;
    tile[c][k] = W[(size_t)(kb + k) * N + nb + c];
  }
  __syncthreads();
#pragma unroll
  for (int s = 0; s < 16; ++s) {
    int n = r0 + s * 4;
    WT[(size_t)(outRowOff + nb + n) * outStride + kb + c] = f2b(tile[n][c]);
  }
}

// ---------------- bf16 MFMA GEMM, C = A(MxK) * BT(NxK)^T + bias ----------------
__launch_bounds__(256, 2)
__global__ void gemm_bt(const short* __restrict__ A, const short* __restrict__ BT,
                        float* __restrict__ C, const float* __restrict__ bias,
                        int M, int N, int K) {
  __shared__ __align__(16) short lA[128 * 32];
  __shared__ __align__(16) short lB[128 * 32];
  const int tid = threadIdx.x;
  const int lane = tid & 63;
  const int wv = tid >> 6;
  const int wr = wv >> 1, wc = wv & 1;
  const int q4 = lane >> 4, l15 = lane & 15;
  const int bm = blockIdx.y * 128, bn = blockIdx.x * 128;

  const short* Ag = A + (size_t)(bm + (tid >> 2)) * K + ((tid & 3) << 3);
  const short* Bg = BT + (size_t)(bn + (tid >> 2)) * K + ((tid & 3) << 3);
  short* lA0 = lA + wv * 512;
  short* lB0 = lB + wv * 512;

  f32x4 acc[4][4];
  const f32x4 fz = {0.f, 0.f, 0.f, 0.f};
#pragma unroll
  for (int i = 0; i < 4; ++i)
#pragma unroll
    for (int j = 0; j < 4; ++j) acc[i][j] = fz;

  for (int k0 = 0; k0 < K; k0 += 32) {
    gl_lds16(Ag + k0, lA0);
    gl_lds16(Ag + (size_t)64 * K + k0, lA0 + 2048);
    gl_lds16(Bg + k0, lB0);
    gl_lds16(Bg + (size_t)64 * K + k0, lB0 + 2048);
    __syncthreads();
    short8 af[4], bf[4];
#pragma unroll
    for (int i = 0; i < 4; ++i) af[i] = *(const short8*)(lA + (wr * 64 + i * 16 + l15) * 32 + q4 * 8);
#pragma unroll
    for (int i = 0; i < 4; ++i) bf[i] = *(const short8*)(lB + (wc * 64 + i * 16 + l15) * 32 + q4 * 8);
#pragma unroll
    for (int mi = 0; mi < 4; ++mi)
#pragma unroll
      for (int ni = 0; ni < 4; ++ni)
        acc[mi][ni] = __builtin_amdgcn_mfma_f32_16x16x32_bf16(af[mi], bf[ni], acc[mi][ni], 0, 0, 0);
    __syncthreads();
  }

#pragma unroll
  for (int mi = 0; mi < 4; ++mi) {
    int row = bm + wr * 64 + mi * 16 + q4 * 4;
#pragma unroll
    for (int ni = 0; ni < 4; ++ni) {
      int col = bn + wc * 64 + ni * 16 + l15;
      float bb = bias ? bias[col] : 0.f;
#pragma unroll
      for (int r = 0; r < 4; ++r)
        C[(size_t)(row + r) * N + col] = acc[mi][ni][r] + bb;
    }
  }
}

// ---------------- RoPE (+bias); Q scaled by (1/8)*log2(e) so attn runs in base-2 ----------------
__global__ void rope_qk(const float* __restrict__ Cqkv,
                        const float* __restrict__ bq, const float* __restrict__ bk,
                        short* __restrict__ Qb, short* __restrict__ Kb) {
  int idx = blockIdx.x * 256 + threadIdx.x;
  int d2 = idx & 31;
  int rem = idx >> 5;
  int slot = rem % 40;
  int rem2 = rem / 40;
  int t = rem2 & 1023;
  int b = rem2 >> 10;
  size_t rowbase = (size_t)(b * 1024 + t) * 3072;
  float theta = expf(-(float)d2 * (9.210340371976184f / 32.0f));
  float ang = (float)(t + 1) * theta;
  float sn = sinf(ang), cs = cosf(ang);
  if (slot < 32) {
    int h = slot;
    int cb = h * 64 + d2;
    float x0 = Cqkv[rowbase + cb] + bq[cb];
    float x1 = Cqkv[rowbase + cb + 32] + bq[cb + 32];
    const float s2 = 0.18033688011112042f;  // 0.125 * log2(e)
    float y0 = (x0 * cs - x1 * sn) * s2;
    float y1 = (x1 * cs + x0 * sn) * s2;
    size_t ob = ((size_t)(b * 32 + h) * 1024 + t) * 64 + d2;
    Qb[ob] = f2b(y0);
    Qb[ob + 32] = f2b(y1);
  } else {
    int h = slot - 32;
    int cb = h * 64 + d2;
    float x0 = Cqkv[rowbase + 2048 + cb] + bk[cb];
    float x1 = Cqkv[rowbase + 2048 + cb + 32] + bk[cb + 32];
    float y0 = x0 * cs - x1 * sn;
    float y1 = x1 * cs + x0 * sn;
    size_t ob = ((size_t)(b * 8 + h) * 1024 + t) * 64 + d2;
    Kb[ob] = f2b(y0);
    Kb[ob + 32] = f2b(y1);
  }
}

// ---------------- V: (b,t,hkv,d) slice of Cqkv -> VT (b,hkv,d,t) bf16 ----------------
__global__ void vtrans_kernel(const float* __restrict__ Cqkv, const float* __restrict__ bv,
                              short* __restrict__ VTb) {
  __shared__ float tile[64][65];
  const int tt = blockIdx.x, h = blockIdx.y, b = blockIdx.z;
  const int tid = threadIdx.x;
  const int d = tid & 63, r0 = tid >> 6;
#pragma unroll
  for (int s = 0; s < 16; ++s) {
    int tl = r0 + s * 4;
    tile[d][tl] = Cqkv[(size_t)(b * 1024 + tt * 64 + tl) * 3072 + 2560 + h * 64 + d] + bv[h * 64 + d];
  }
  __syncthreads();
  const int tl = tid & 63, d0 = tid >> 6;
#pragma unroll
  for (int s = 0; s < 16; ++s) {
    int dd = d0 + s * 4;
    VTb[((size_t)((b * 8 + h) * 64 + dd)) * 1024 + tt * 64 + tl] = f2b(tile[dd][tl]);
  }
}

// ---------------- flash attention v2: barrier-free, wave-autonomous ----------------
// grid (8, 32, B); block 256 = 4 waves; wave w owns q rows [qt*128 + w*32, +32) as 2 m-frags.
// K / V^T fragments loaded straight from global (L2-warm) into registers; no __syncthreads.
// Scores are base-2 (log2e/8 folded into Q); row-max via DPP row_ror; row-sum via ones-MFMA.
#define PROW 72  // padded LDS row stride (shorts); 144B = 16B-aligned, breaks 8-way conflicts
__launch_bounds__(256, 2)
__global__ void attn2_kernel(const short* __restrict__ Qb, const short* __restrict__ Kb,
                             const short* __restrict__ VTb, short* __restrict__ AO) {
  __shared__ __align__(16) short lP[4 * 2 * 16 * PROW];
  const int tid = threadIdx.x;
  const int lane = tid & 63, w = tid >> 6;
  const int q4 = lane >> 4, l15 = lane & 15;
  const int qt = (int)gridDim.x - 1 - (int)blockIdx.x;  // heavy q-tiles dispatch first
  const int h = blockIdx.y, b = blockIdx.z;
  const int hkv = h >> 2;
  const int qb = qt * 128 + w * 32;       // wave's first q row
  const int niter = (qb >> 6) + 1;        // causal k-tiles of 64

  const short* Qg = Qb + (size_t)(b * 32 + h) * (1024 * 64);
  const short* Kg = Kb + (size_t)(b * 8 + hkv) * (1024 * 64);
  const short* Vg = VTb + (size_t)(b * 8 + hkv) * (64 * 1024);
  short* lPw = lP + w * (2 * 16 * PROW);

  // Q fragments: A-operand, m=l15, k=half*32+q4*8+j
  short8 qf[2][2];
#pragma unroll
  for (int mf = 0; mf < 2; ++mf) {
    const short* qr = Qg + (size_t)(qb + mf * 16 + l15) * 64 + q4 * 8;
    qf[mf][0] = *(const short8*)(qr);
    qf[mf][1] = *(const short8*)(qr + 32);
  }

  const f32x4 fz = {0.f, 0.f, 0.f, 0.f};
  f32x4 o[2][4], ol[2];
  float m_i[2][4];
#pragma unroll
  for (int mf = 0; mf < 2; ++mf) {
    ol[mf] = fz;
#pragma unroll
    for (int i = 0; i < 4; ++i) { o[mf][i] = fz; m_i[mf][i] = -1e30f; }
  }

  short8 ones;
#pragma unroll
  for (int i = 0; i < 8; ++i) ones[i] = (short)0x3F80;  // bf16 1.0

  for (int kt = 0; kt < niter; ++kt) {
    const short* Kt = Kg + (size_t)kt * 4096 + l15 * 64 + q4 * 8;
    const short* Vt = Vg + (size_t)l15 * 1024 + kt * 64 + q4 * 8;
    short8 kf0[4], kf1[4], vf0[4], vf1[4];
#pragma unroll
    for (int nt = 0; nt < 4; ++nt) {
      kf0[nt] = *(const short8*)(Kt + nt * 1024);
      kf1[nt] = *(const short8*)(Kt + nt * 1024 + 32);
    }
#pragma unroll
    for (int dt = 0; dt < 4; ++dt) {
      vf0[dt] = *(const short8*)(Vt + dt * 16384);
      vf1[dt] = *(const short8*)(Vt + dt * 16384 + 32);
    }

    const bool lastTile = (kt == niter - 1);
#pragma unroll
    for (int mf = 0; mf < 2; ++mf) {
      f32x4 s[4];
#pragma unroll
      for (int nt = 0; nt < 4; ++nt) {
        f32x4 z = __builtin_amdgcn_mfma_f32_16x16x32_bf16(qf[mf][0], kf0[nt], fz, 0, 0, 0);
        s[nt] = __builtin_amdgcn_mfma_f32_16x16x32_bf16(qf[mf][1], kf1[nt], z, 0, 0, 0);
      }

      short* lPm = lPw + mf * (16 * PROW);
#pragma unroll
      for (int r = 0; r < 4; ++r) {
        const int qrow = qb + mf * 16 + q4 * 4 + r;
        if (lastTile) {
          const int col = kt * 64 + l15;
#pragma unroll
          for (int nt = 0; nt < 4; ++nt)
            if (col + nt * 16 > qrow) s[nt][r] = -1e30f;
        }
        float mx = fmaxf(fmaxf(s[0][r], s[1][r]), fmaxf(s[2][r], s[3][r]));
        mx = dpp_max_step<0x128>(mx);  // row_ror:8
        mx = dpp_max_step<0x124>(mx);  // row_ror:4
        mx = dpp_max_step<0x122>(mx);  // row_ror:2
        mx = dpp_max_step<0x121>(mx);  // row_ror:1
        float mnew = fmaxf(m_i[mf][r], mx);
        float alpha = exp2_fast(fmaxf(m_i[mf][r] - mnew, -100.f));
        m_i[mf][r] = mnew;
#pragma unroll
        for (int dt = 0; dt < 4; ++dt) o[mf][dt][r] *= alpha;
        ol[mf][r] *= alpha;
#pragma unroll
        for (int nt = 0; nt < 4; ++nt) {
          float p = exp2_fast(fmaxf(s[nt][r] - mnew, -100.f));
          lPm[(q4 * 4 + r) * PROW + nt * 16 + l15] = f2b(p);
        }
      }

      // P: C-layout -> A-layout (per-wave LDS, DS in-order within wave)
      short8 pf0 = *(const short8*)(lPm + l15 * PROW + q4 * 8);
      short8 pf1 = *(const short8*)(lPm + l15 * PROW + 32 + q4 * 8);

      ol[mf] = __builtin_amdgcn_mfma_f32_16x16x32_bf16(pf0, ones, ol[mf], 0, 0, 0);
      ol[mf] = __builtin_amdgcn_mfma_f32_16x16x32_bf16(pf1, ones, ol[mf], 0, 0, 0);
#pragma unroll
      for (int dt = 0; dt < 4; ++dt) {
        o[mf][dt] = __builtin_amdgcn_mfma_f32_16x16x32_bf16(pf0, vf0[dt], o[mf][dt], 0, 0, 0);
        o[mf][dt] = __builtin_amdgcn_mfma_f32_16x16x32_bf16(pf1, vf1[dt], o[mf][dt], 0, 0, 0);
      }
    }
  }

#pragma unroll
  for (int mf = 0; mf < 2; ++mf)
#pragma unroll
    for (int r = 0; r < 4; ++r) {
      float inv = __builtin_amdgcn_rcpf(ol[mf][r]);
      int row = qb + mf * 16 + q4 * 4 + r;
#pragma unroll
      for (int dt = 0; dt < 4; ++dt)
        AO[(size_t)(b * 1024 + row) * 2048 + h * 64 + dt * 16 + l15] = f2b(o[mf][dt][r] * inv);
    }
}

extern "C" void kernel_launch(void* const* d_in, const int* in_sizes, int n_in,
                              void* d_out, int out_size, void* d_ws, size_t ws_size,
                              hipStream_t stream) {
  const float* x  = (const float*)d_in[0];
  const float* wq = (const float*)d_in[1];
  const float* bq = (const float*)d_in[2];
  const float* wk = (const float*)d_in[3];
  const float* bk = (const float*)d_in[4];
  const float* wv = (const float*)d_in[5];
  const float* bv = (const float*)d_in[6];
  const float* wo = (const float*)d_in[7];
  const float* bo = (const float*)d_in[8];
  float* out = (float*)d_out;
  const int B = in_sizes[0] / (1024 * 2048);
  const int M = B * 1024;

  char* ws = (char*)d_ws;
  size_t off = 0;
  auto alloc = [&](size_t bytes) -> char* {
    char* p = ws + off;
    off += (bytes + 255) & ~(size_t)255;
    return p;
  };
  short* xb    = (short*)alloc((size_t)M * 2048 * 2);
  short* WqkvT = (short*)alloc((size_t)3072 * 2048 * 2);
  short* woT   = (short*)alloc((size_t)2048 * 2048 * 2);
  float* Cqkv  = (float*)alloc((size_t)M * 3072 * 4);
  short* Qb    = (short*)alloc((size_t)B * 32 * 1024 * 64 * 2);  // (b,h,t,d)
  short* Kb    = (short*)alloc((size_t)B * 8 * 1024 * 64 * 2);   // (b,hkv,t,d)
  short* VTb   = (short*)alloc((size_t)B * 8 * 64 * 1024 * 2);   // (b,hkv,d,t)
  short* AO    = (short*)alloc((size_t)M * 2048 * 2);            // (b,t,E) bf16

  cast_x_kernel<<<(M * 2048 / 4 + 255) / 256, 256, 0, stream>>>(x, xb, M * 2048 / 4);
  wtrans_kernel<<<dim3(2048 / 64, 2048 / 64), 256, 0, stream>>>(wq, WqkvT, 2048, 0, 2048);
  wtrans_kernel<<<dim3(512 / 64, 2048 / 64), 256, 0, stream>>>(wk, WqkvT, 512, 2048, 2048);
  wtrans_kernel<<<dim3(512 / 64, 2048 / 64), 256, 0, stream>>>(wv, WqkvT, 512, 2560, 2048);
  wtrans_kernel<<<dim3(2048 / 64, 2048 / 64), 256, 0, stream>>>(wo, woT, 2048, 0, 2048);
  gemm_bt<<<dim3(3072 / 128, M / 128), 256, 0, stream>>>(xb, WqkvT, Cqkv, nullptr, M, 3072, 2048);
  rope_qk<<<(B * 1024 * 40 * 32) / 256, 256, 0, stream>>>(Cqkv, bq, bk, Qb, Kb);
  vtrans_kernel<<<dim3(16, 8, B), 256, 0, stream>>>(Cqkv, bv, VTb);
  attn2_kernel<<<dim3(8, 32, B), 256, 0, stream>>>(Qb, Kb, VTb, AO);
  gemm_bt<<<dim3(2048 / 128, M / 128), 256, 0, stream>>>(AO, woT, out, bo, M, 2048, 2048);
}